// Round 10
// baseline (94.155 us; speedup 1.0000x reference)
//
#include <hip/hip_runtime.h>

#define S 2048
#define D 512
#define NH 32
#define DHD 16
#define DFF 1024
#define EPS 1e-5f
#define C1 0.36067376022224085f  // (1/sqrt(16)) * log2(e), folded into Q

typedef unsigned short u16;
typedef __attribute__((ext_vector_type(8))) short short8;
typedef __attribute__((ext_vector_type(4))) float f32x4;
typedef __attribute__((ext_vector_type(16))) float f32x16;
typedef __attribute__((ext_vector_type(4))) unsigned short us4;

#define GL_LDS(gsrc, ldst)                                                   \
  __builtin_amdgcn_global_load_lds(                                          \
      (const __attribute__((address_space(1))) unsigned int*)(gsrc),         \
      (__attribute__((address_space(3))) unsigned int*)(ldst), 16, 0, 0)

static __device__ __forceinline__ u16 f2bf(float f) {
  union { float f; unsigned int i; } c; c.f = f;
  unsigned int x = c.i;
  return (u16)((x + 0x7fffu + ((x >> 16) & 1u)) >> 16);
}
static __device__ __forceinline__ float bf2f(u16 v) {
  union { unsigned int i; float f; } c; c.i = ((unsigned int)v) << 16;
  return c.f;
}

static __device__ __forceinline__ float tsum16(const float* p) {
  float a0 = p[0] + p[1], a1 = p[2] + p[3], a2 = p[4] + p[5], a3 = p[6] + p[7];
  float a4 = p[8] + p[9], a5 = p[10] + p[11], a6 = p[12] + p[13], a7 = p[14] + p[15];
  float b0 = a0 + a1, b1 = a2 + a3, b2 = a4 + a5, b3 = a6 + a7;
  return (b0 + b1) + (b2 + b3);
}

// ---------------- fused prologue: weight prep + ln0 ----------------
// bz [0,2048): weight fragment prep; [2048,2560): ln0 rows.
__global__ __launch_bounds__(256) void prologue_kernel(
    const float* __restrict__ x,
    const float* __restrict__ g0, const float* __restrict__ b0,
    const float* __restrict__ gq, const float* __restrict__ bq,
    const float* __restrict__ gk, const float* __restrict__ bk,
    const float* __restrict__ gv, const float* __restrict__ bv,
    float* __restrict__ xn, u16* __restrict__ qin, u16* __restrict__ kin,
    u16* __restrict__ vin,
    const float* __restrict__ Wq, const float* __restrict__ Wk,
    const float* __restrict__ Wv, const float* __restrict__ Wo,
    const float* __restrict__ W1, const float* __restrict__ W2,
    u16* __restrict__ Fq, u16* __restrict__ Fk,
    u16* __restrict__ Fv, u16* __restrict__ Fo,
    u16* __restrict__ F1, u16* __restrict__ F2) {
  int bz = blockIdx.x;
  int t = threadIdx.x;
  if (bz < 2048) {
    __shared__ float tile[32][33];
    const float* W;
    u16* F;
    int K, N, n0, k0;
    if (bz < 1024) {
      int wi = bz >> 8, tl = bz & 255;
      W = wi == 0 ? Wq : wi == 1 ? Wk : wi == 2 ? Wv : Wo;
      F = wi == 0 ? Fq : wi == 1 ? Fk : wi == 2 ? Fv : Fo;
      K = 512; N = 512;
      n0 = (tl & 15) * 32; k0 = (tl >> 4) * 32;
    } else if (bz < 1536) {
      int tl = bz - 1024;
      W = W1; F = F1; K = 512; N = 1024;
      n0 = (tl & 31) * 32; k0 = (tl >> 5) * 32;
    } else {
      int tl = bz - 1536;
      W = W2; F = F2; K = 1024; N = 512;
      n0 = (tl & 15) * 32; k0 = (tl >> 4) * 32;
    }
    int tx = t & 31, ty = t >> 5;
#pragma unroll
    for (int i = 0; i < 4; ++i)
      tile[ty + 8 * i][tx] = W[(size_t)(k0 + ty + 8 * i) * N + n0 + tx];
    __syncthreads();
    int k = k0 + tx;
    int kpart = ((k >> 3) & 1) * 32;
    int kj = k & 7;
#pragma unroll
    for (int i = 0; i < 4; ++i) {
      int n = n0 + ty + 8 * i;
      size_t I = (size_t)((n >> 5) * (K >> 4) + (k >> 4)) * 512 + ((n & 31) + kpart) * 8 + kj;
      F[I] = f2bf(tile[tx][ty + 8 * i]);
    }
    return;
  }
  // ---- ln0 ----
  int w = t >> 6, lane = t & 63;
  int row = (bz - 2048) * 4 + w;
  int c = lane * 8;
  const float* xr = x + (size_t)row * D + c;
  float4 xa = *(const float4*)xr;
  float4 xb = *(const float4*)(xr + 4);
  float a[8] = {xa.x, xa.y, xa.z, xa.w, xb.x, xb.y, xb.z, xb.w};
  float s = 0.0f, ss = 0.0f;
#pragma unroll
  for (int i = 0; i < 8; ++i) { s += a[i]; ss += a[i] * a[i]; }
#pragma unroll
  for (int m = 1; m <= 32; m <<= 1) { s += __shfl_xor(s, m); ss += __shfl_xor(ss, m); }
  float mean = s * (1.0f / D);
  float rs = rsqrtf(ss * (1.0f / D) - mean * mean + EPS);
  float4 ga = *(const float4*)(g0 + c), gb = *(const float4*)(g0 + c + 4);
  float4 ba = *(const float4*)(b0 + c), bb = *(const float4*)(b0 + c + 4);
  float gg[8] = {ga.x, ga.y, ga.z, ga.w, gb.x, gb.y, gb.z, gb.w};
  float bbv[8] = {ba.x, ba.y, ba.z, ba.w, bb.x, bb.y, bb.z, bb.w};
  float y[8];
  float s2 = 0.0f, ss2 = 0.0f;
#pragma unroll
  for (int i = 0; i < 8; ++i) {
    y[i] = (a[i] - mean) * rs * gg[i] + bbv[i];
    s2 += y[i]; ss2 += y[i] * y[i];
  }
  float* xo = xn + (size_t)row * D + c;
  *(float4*)xo = {y[0], y[1], y[2], y[3]};
  *(float4*)(xo + 4) = {y[4], y[5], y[6], y[7]};
#pragma unroll
  for (int m = 1; m <= 32; m <<= 1) { s2 += __shfl_xor(s2, m); ss2 += __shfl_xor(ss2, m); }
  float m2 = s2 * (1.0f / D);
  float rs2 = rsqrtf(ss2 * (1.0f / D) - m2 * m2 + EPS);
  float cn[8];
#pragma unroll
  for (int i = 0; i < 8; ++i) cn[i] = (y[i] - m2) * rs2;
  size_t o = (size_t)row * D + c;
#pragma unroll
  for (int br = 0; br < 3; ++br) {
    const float* gp = br == 0 ? gq : br == 1 ? gk : gv;
    const float* bp = br == 0 ? bq : br == 1 ? bk : bv;
    u16* op = br == 0 ? qin : br == 1 ? kin : vin;
    float4 g1 = *(const float4*)(gp + c), g2 = *(const float4*)(gp + c + 4);
    float4 b1 = *(const float4*)(bp + c), b2 = *(const float4*)(bp + c + 4);
    float gv2[8] = {g1.x, g1.y, g1.z, g1.w, g2.x, g2.y, g2.z, g2.w};
    float bv2[8] = {b1.x, b1.y, b1.z, b1.w, b2.x, b2.y, b2.z, b2.w};
    us4 o1, o2;
#pragma unroll
    for (int i = 0; i < 4; ++i) o1[i] = f2bf(cn[i] * gv2[i] + bv2[i]);
#pragma unroll
    for (int i = 0; i < 4; ++i) o2[i] = f2bf(cn[4 + i] * gv2[4 + i] + bv2[4 + i]);
    *(us4*)(op + o) = o1;
    *(us4*)(op + o + 4) = o2;
  }
}

// ---------------- GEMM: 64x64 block, BK=64, A via global_load_lds, B in regs ----------------
static __device__ __forceinline__ void stageA(const u16* __restrict__ A, int K,
                                              int m0, int kk, u16* As, int t) {
  int r = t >> 3, sl = t & 7;
  GL_LDS(A + (size_t)(m0 + r) * K + kk + ((sl ^ (r & 7)) * 8), As + t * 8);
  int r2 = r + 32;
  GL_LDS(A + (size_t)(m0 + r2) * K + kk + ((sl ^ (r2 & 7)) * 8), As + (t + 256) * 8);
}

static __device__ __forceinline__ void gemm64_acc(
    const u16* __restrict__ A, const u16* __restrict__ Wf, int K, int m0,
    int n32base, u16 (*As)[4096], f32x16& acc) {
  int t = threadIdx.x, w = t >> 6, lane = t & 63;
  int wm = w >> 1, wn = w & 1;
  int l31 = lane & 31, hi5 = lane >> 5;
  const u16* bp = Wf + (size_t)(n32base + wn) * (K >> 4) * 512 + lane * 8;
  stageA(A, K, m0, 0, As[0], t);
  short8 bcur[4], bnxt[4];
#pragma unroll
  for (int ks = 0; ks < 4; ++ks) bcur[ks] = *(const short8*)(bp + ks * 512);
  __syncthreads();
  int pb = 0;
  int arow = wm * 32 + l31;
  int abase = arow * 64;
  for (int kk = 0; kk < K; kk += 64) {
    if (kk + 64 < K) {
      stageA(A, K, m0, kk + 64, As[pb ^ 1], t);
      const u16* bp2 = bp + (size_t)(kk + 64) * 32;
#pragma unroll
      for (int ks = 0; ks < 4; ++ks) bnxt[ks] = *(const short8*)(bp2 + ks * 512);
    }
#pragma unroll
    for (int ks = 0; ks < 4; ++ks) {
      int slot = (ks * 2 + hi5) ^ (arow & 7);
      short8 af = *(const short8*)&As[pb][abase + slot * 8];
      acc = __builtin_amdgcn_mfma_f32_32x32x16_bf16(af, bcur[ks], acc, 0, 0, 0);
    }
    __syncthreads();
    pb ^= 1;
#pragma unroll
    for (int ks = 0; ks < 4; ++ks) bcur[ks] = bnxt[ks];
  }
}

template <bool RELU, bool RESID, bool OUTBF>
__global__ __launch_bounds__(256) void gemm_kernel(
    const u16* __restrict__ A, const u16* __restrict__ Wf,
    const float* __restrict__ bias, const float* __restrict__ resid,
    float* __restrict__ outf, u16* __restrict__ outb, int N, int K) {
  __shared__ u16 As[2][4096];
  int m0 = blockIdx.x * 64, n0 = blockIdx.y * 64;
  f32x16 acc = {};
  gemm64_acc(A, Wf, K, m0, blockIdx.y * 2, As, acc);
  int t = threadIdx.x, w = t >> 6, lane = t & 63;
  int wm = w >> 1, wn = w & 1;
  int l31 = lane & 31, hi5 = lane >> 5;
  int col = n0 + wn * 32 + l31;
  float bv = bias[col];
#pragma unroll
  for (int r = 0; r < 16; ++r) {
    int row = m0 + wm * 32 + (r & 3) + 8 * (r >> 2) + 4 * hi5;
    float v = acc[r] + bv;
    if (RELU) v = fmaxf(v, 0.0f);
    if (RESID) v += resid[(size_t)row * N + col];
    if (OUTBF)
      outb[(size_t)row * N + col] = f2bf(v);
    else
      outf[(size_t)row * N + col] = v;
  }
}

// ---------------- FFN1 GEMM with fused LayerNorm on A ----------------
// A = LN(outb)*g+b computed on the fly: per-block row stats, reg-staged
// normalize + bf16 pack into the same swizzled LDS layout as stageA.
__global__ __launch_bounds__(256) void gemm_ffn1(
    const float* __restrict__ outb, const float* __restrict__ lng,
    const float* __restrict__ lnb, const u16* __restrict__ Wf,
    const float* __restrict__ bias, u16* __restrict__ out) {
  __shared__ u16 As[2][4096];
  __shared__ float sMean[64], sRs[64];
  int t = threadIdx.x, w = t >> 6, lane = t & 63;
  int m0 = blockIdx.x * 64, n0 = blockIdx.y * 64;
  // ---- per-row LN stats (4 threads per row) ----
  {
    int r = t >> 2, qd = t & 3;
    const float* rp = outb + (size_t)(m0 + r) * D + qd * 128;
    float s = 0.0f, ss = 0.0f;
#pragma unroll
    for (int i = 0; i < 32; ++i) {
      float4 v = *(const float4*)(rp + i * 4);
      s += v.x + v.y + v.z + v.w;
      ss += v.x * v.x + v.y * v.y + v.z * v.z + v.w * v.w;
    }
    s += __shfl_xor(s, 1); ss += __shfl_xor(ss, 1);
    s += __shfl_xor(s, 2); ss += __shfl_xor(ss, 2);
    if (qd == 0) {
      float mean = s * (1.0f / D);
      sMean[r] = mean;
      sRs[r] = rsqrtf(ss * (1.0f / D) - mean * mean + EPS);
    }
  }
  __syncthreads();
  const int sr = t >> 3, sl = t & 7, sr2 = sr + 32;
  const float mean1 = sMean[sr], rs1 = sRs[sr];
  const float mean2 = sMean[sr2], rs2 = sRs[sr2];
  const int col0 = (sl ^ (sr & 7)) * 8;  // same swizzle for sr and sr2

  float ra[8], rb[8], rg[8], rbb[8];
  auto ldStage = [&](int kk) {
    int cc = kk + col0;
    float4 v0 = *(const float4*)(outb + (size_t)(m0 + sr) * D + cc);
    float4 v1 = *(const float4*)(outb + (size_t)(m0 + sr) * D + cc + 4);
    float4 v2 = *(const float4*)(outb + (size_t)(m0 + sr2) * D + cc);
    float4 v3 = *(const float4*)(outb + (size_t)(m0 + sr2) * D + cc + 4);
    ra[0]=v0.x; ra[1]=v0.y; ra[2]=v0.z; ra[3]=v0.w; ra[4]=v1.x; ra[5]=v1.y; ra[6]=v1.z; ra[7]=v1.w;
    rb[0]=v2.x; rb[1]=v2.y; rb[2]=v2.z; rb[3]=v2.w; rb[4]=v3.x; rb[5]=v3.y; rb[6]=v3.z; rb[7]=v3.w;
    float4 g0 = *(const float4*)(lng + cc), g1 = *(const float4*)(lng + cc + 4);
    float4 b0 = *(const float4*)(lnb + cc), b1 = *(const float4*)(lnb + cc + 4);
    rg[0]=g0.x; rg[1]=g0.y; rg[2]=g0.z; rg[3]=g0.w; rg[4]=g1.x; rg[5]=g1.y; rg[6]=g1.z; rg[7]=g1.w;
    rbb[0]=b0.x; rbb[1]=b0.y; rbb[2]=b0.z; rbb[3]=b0.w; rbb[4]=b1.x; rbb[5]=b1.y; rbb[6]=b1.z; rbb[7]=b1.w;
  };
  auto wrStage = [&](int pb_) {
    us4 o1, o2, o3, o4;
#pragma unroll
    for (int i = 0; i < 4; ++i) {
      o1[i] = f2bf((ra[i] - mean1) * rs1 * rg[i] + rbb[i]);
      o2[i] = f2bf((ra[4 + i] - mean1) * rs1 * rg[4 + i] + rbb[4 + i]);
      o3[i] = f2bf((rb[i] - mean2) * rs2 * rg[i] + rbb[i]);
      o4[i] = f2bf((rb[4 + i] - mean2) * rs2 * rg[4 + i] + rbb[4 + i]);
    }
    *(us4*)&As[pb_][t * 8] = o1;
    *(us4*)&As[pb_][t * 8 + 4] = o2;
    *(us4*)&As[pb_][(t + 256) * 8] = o3;
    *(us4*)&As[pb_][(t + 256) * 8 + 4] = o4;
  };

  int wm = w >> 1, wn = w & 1;
  int l31 = lane & 31, hi5 = lane >> 5;
  const u16* bp = Wf + (size_t)(blockIdx.y * 2 + wn) * (D >> 4) * 512 + lane * 8;
  f32x16 acc = {};
  ldStage(0);
  wrStage(0);
  short8 bcur[4], bnxt[4];
#pragma unroll
  for (int ks = 0; ks < 4; ++ks) bcur[ks] = *(const short8*)(bp + ks * 512);
  __syncthreads();
  int pb = 0;
  int arow = wm * 32 + l31;
  int abase = arow * 64;
  for (int kk = 0; kk < D; kk += 64) {
    if (kk + 64 < D) {
      ldStage(kk + 64);
      const u16* bp2 = bp + (size_t)(kk + 64) * 32;
#pragma unroll
      for (int ks = 0; ks < 4; ++ks) bnxt[ks] = *(const short8*)(bp2 + ks * 512);
    }
#pragma unroll
    for (int ks = 0; ks < 4; ++ks) {
      int slot = (ks * 2 + hi5) ^ (arow & 7);
      short8 af = *(const short8*)&As[pb][abase + slot * 8];
      acc = __builtin_amdgcn_mfma_f32_32x32x16_bf16(af, bcur[ks], acc, 0, 0, 0);
    }
    if (kk + 64 < D) wrStage(pb ^ 1);
    __syncthreads();
    pb ^= 1;
#pragma unroll
    for (int ks = 0; ks < 4; ++ks) bcur[ks] = bnxt[ks];
  }
  int col = n0 + wn * 32 + l31;
  float bv = bias[col];
#pragma unroll
  for (int r = 0; r < 16; ++r) {
    int row = m0 + wm * 32 + (r & 3) + 8 * (r >> 2) + 4 * hi5;
    float v = fmaxf(acc[r] + bv, 0.0f);
    out[(size_t)row * DFF + col] = f2bf(v);
  }
}

// QKV fused GEMM. z=0: Q row-major (scaled by C1). z=1: K fragment layout.
// z=2: V^T fragment layout (attention reads fragments directly from global).
__global__ __launch_bounds__(256) void gemm_qkv(
    const u16* __restrict__ a0, const u16* __restrict__ a1, const u16* __restrict__ a2,
    const u16* __restrict__ w0, const u16* __restrict__ w1, const u16* __restrict__ w2,
    const float* __restrict__ c0, const float* __restrict__ c1, const float* __restrict__ c2,
    u16* __restrict__ Qb, u16* __restrict__ KtG, u16* __restrict__ VtG) {
  __shared__ u16 As[2][4096];
  int z = blockIdx.z;
  const u16* A = z == 0 ? a0 : z == 1 ? a1 : a2;
  const u16* Wf = z == 0 ? w0 : z == 1 ? w1 : w2;
  const float* bias = z == 0 ? c0 : z == 1 ? c1 : c2;
  int m0 = blockIdx.x * 64, n0 = blockIdx.y * 64;
  f32x16 acc = {};
  gemm64_acc(A, Wf, D, m0, blockIdx.y * 2, As, acc);
  int t = threadIdx.x, w = t >> 6, lane = t & 63;
  int wm = w >> 1, wn = w & 1;
  int l31 = lane & 31, hi5 = lane >> 5;
  int col = n0 + wn * 32 + l31;
  float bv = bias[col];
  int h = col >> 4, d = col & 15;
  if (z == 2) {  // vectorized: 4 consecutive rows are contiguous in V layout
#pragma unroll
    for (int rg = 0; rg < 4; ++rg) {
      int row = m0 + wm * 32 + 8 * rg + 4 * hi5;
      us4 pk;
#pragma unroll
      for (int j = 0; j < 4; ++j) pk[j] = f2bf(acc[rg * 4 + j] + bv);
      int I = (((row >> 5) * 4 + ((row >> 3) & 3)) * 16 + d) * 8 + (row & 7);
      *(us4*)(VtG + (size_t)h * 32768 + I) = pk;
    }
  } else {
#pragma unroll
    for (int r = 0; r < 16; ++r) {
      int row = m0 + wm * 32 + (r & 3) + 8 * (r >> 2) + 4 * hi5;
      float v = acc[r] + bv;
      if (z == 0) {
        Qb[(size_t)row * D + col] = f2bf(v * C1);
      } else {
        int I = (((row >> 5) * 2 + (d >> 3)) * 32 + (row & 31)) * 8 + (d & 7);
        KtG[(size_t)h * 32768 + I] = f2bf(v);
      }
    }
  }
}

// ---------------- causal flash attention, split-KV, no-max softmax ----------------
__global__ __launch_bounds__(128) void attn_kernel(const u16* __restrict__ Qb,
                                                   const u16* __restrict__ KtG,
                                                   const u16* __restrict__ VtG,
                                                   u16* __restrict__ ctx,
                                                   u16* __restrict__ part) {
  __shared__ u16 Pl[2][2048];

  const int t = threadIdx.x, w = t >> 6, lane = t & 63;
  const int h = blockIdx.y;
  const int f = 143 - blockIdx.x;  // longest chunks dispatched first
  int g = (int)((sqrtf((float)(1 + 2 * f)) - 1.0f) * 0.5f);
  while (2 * (g + 1) * (g + 2) <= f) ++g;
  while (2 * g * (g + 1) > f) --g;
  const int fg = f - 2 * g * (g + 1);
  const int qt = 4 * g + fg / (g + 1);
  const int c = fg - (fg / (g + 1)) * (g + 1);
  const int t0 = 4 * c;
  const int t1 = (4 * c + 3 < qt) ? 4 * c + 3 : qt;

  const int q0w = qt * 64 + w * 32;
  const int lq = lane & 31, hi = lane >> 5;
  const int l16 = lane & 15, g4 = lane >> 4;

  short8 qf = *(const short8*)(Qb + (size_t)(q0w + lq) * D + h * DHD + hi * 8);
  const u16* kp = KtG + (size_t)h * 32768 + (size_t)t0 * 1024 + hi * 256 + lq * 8;
  const u16* vp = VtG + (size_t)h * 32768 + (size_t)t0 * 1024 + g4 * 128 + l16 * 8;

  f32x4 acc[2] = {};
  float Lrun = 0.0f;

  short8 kf0 = *(const short8*)kp;
  short8 kf1 = *(const short8*)(kp + 512);
  short8 vf0 = *(const short8*)vp;
  short8 vf1 = *(const short8*)(vp + 512);

  u16* Pw = &Pl[w][0];
  const int pwr = (lq >> 4) * 1024 + (lq & 15) * 8 + 4 * hi;  // P write base
  const int prd = g4 * 128 + l16 * 8;                          // P read base

  for (int tt = t0; tt <= t1; ++tt) {
    const int kv0 = tt * 64;
    const bool v1 = (kv0 + 32) <= (q0w + 31);
    f32x16 z = {};
    f32x16 st0 = __builtin_amdgcn_mfma_f32_32x32x16_bf16(kf0, qf, z, 0, 0, 0);
    f32x16 st1 = z;
    if (v1) st1 = __builtin_amdgcn_mfma_f32_32x32x16_bf16(kf1, qf, z, 0, 0, 0);

    short8 nk0, nk1, nv0, nv1;
    const bool more = (tt < t1);
    if (more) {  // issue next-tile loads early; they hide under softmax
      kp += 1024; vp += 1024;
      nk0 = *(const short8*)kp;
      nk1 = *(const short8*)(kp + 512);
      nv0 = *(const short8*)vp;
      nv1 = *(const short8*)(vp + 512);
    }

    // ---- mask (diag tiles) + exp2, no max subtraction ----
    float p0[16], p1[16];
    const int thr0 = q0w + lq - kv0 - 4 * hi;
    if (kv0 + 31 > q0w) {
#pragma unroll
      for (int r = 0; r < 16; ++r) {
        const int rc = (r & 3) + 8 * (r >> 2);
        p0[r] = (rc > thr0) ? -1e30f : st0[r];
      }
    } else {
#pragma unroll
      for (int r = 0; r < 16; ++r) p0[r] = st0[r];
    }
#pragma unroll
    for (int r = 0; r < 16; ++r) p0[r] = exp2f(p0[r]);
    float sum = tsum16(p0);
    if (v1) {
      const int thr1 = thr0 - 32;
      if (kv0 + 63 > q0w) {
#pragma unroll
        for (int r = 0; r < 16; ++r) {
          const int rc = (r & 3) + 8 * (r >> 2);
          p1[r] = (rc > thr1) ? -1e30f : st1[r];
        }
      } else {
#pragma unroll
        for (int r = 0; r < 16; ++r) p1[r] = st1[r];
      }
#pragma unroll
      for (int r = 0; r < 16; ++r) p1[r] = exp2f(p1[r]);
      sum += tsum16(p1);
    }
    sum += __shfl_xor(sum, 32);
    Lrun += sum;

    // ---- pack P (cvt_pk) into swizzled per-wave LDS ----
#pragma unroll
    for (int k = 0; k < 4; ++k) {
      unsigned int w0, w1;
      asm("v_cvt_pk_bf16_f32 %0, %1, %2" : "=v"(w0) : "v"(p0[4 * k]), "v"(p0[4 * k + 1]));
      asm("v_cvt_pk_bf16_f32 %0, %1, %2" : "=v"(w1) : "v"(p0[4 * k + 2]), "v"(p0[4 * k + 3]));
      uint2 pv; pv.x = w0; pv.y = w1;
      *(uint2*)&Pw[(pwr + k * 128) ^ (k << 4)] = pv;
    }
    if (v1) {
#pragma unroll
      for (int k = 0; k < 4; ++k) {
        unsigned int w0, w1;
        asm("v_cvt_pk_bf16_f32 %0, %1, %2" : "=v"(w0) : "v"(p1[4 * k]), "v"(p1[4 * k + 1]));
        asm("v_cvt_pk_bf16_f32 %0, %1, %2" : "=v"(w1) : "v"(p1[4 * k + 2]), "v"(p1[4 * k + 3]));
        uint2 pv; pv.x = w0; pv.y = w1;
        *(uint2*)&Pw[(pwr + 512 + k * 128) ^ (k << 4)] = pv;
      }
    }

    // ---- PV (V fragments live in registers) ----
#pragma unroll
    for (int sx = 0; sx < 2; ++sx) {
      if (sx == 0 || v1) {
        short8 vf = sx ? vf1 : vf0;
#pragma unroll
        for (int sq = 0; sq < 2; ++sq) {
          short8 pf = *(const short8*)&Pw[(sq * 1024 + sx * 512 + prd) ^ (g4 << 4)];
          acc[sq] = __builtin_amdgcn_mfma_f32_16x16x32_bf16(pf, vf, acc[sq], 0, 0, 0);
        }
      }
    }

    if (more) { kf0 = nk0; kf1 = nk1; vf0 = nv0; vf1 = nv1; }
  }

  if (g == 0) {  // single chunk: direct output
#pragma unroll
    for (int sq = 0; sq < 2; ++sq)
#pragma unroll
      for (int r = 0; r < 4; ++r) {
        int qlr = sq * 16 + g4 * 4 + r;
        float lv = __shfl(Lrun, qlr);
        float inv = __builtin_amdgcn_rcpf(lv);
        ctx[(size_t)(q0w + qlr) * D + h * DHD + l16] = f2bf(acc[sq][r] * inv);
      }
  } else {
    // partial row: 20 u16 = [L f32][16 x bf16 O][pad]
    const int pslot = 2 * g * (g + 1) + (qt - 4 * g) * (g + 1) - 4 + c;
    u16* ps = part + ((size_t)(h * 140 + pslot)) * 1280;
#pragma unroll
    for (int sq = 0; sq < 2; ++sq)
#pragma unroll
      for (int r = 0; r < 4; ++r) {
        int qlocal = w * 32 + sq * 16 + g4 * 4 + r;
        ps[qlocal * 20 + 2 + l16] = f2bf(acc[sq][r]);
      }
    if (hi == 0) {
      *(float*)(ps + (w * 32 + lq) * 20) = Lrun;
    }
  }
}

// ---------------- merge split-KV partials (qt >= 4): pure (O,L) sums ----------------
__global__ __launch_bounds__(64) void attn_merge(const u16* __restrict__ part,
                                                 u16* __restrict__ ctx) {
  int qt = 4 + blockIdx.x, h = blockIdx.y, tq = threadIdx.x;
  int g = qt >> 2, nc = g + 1;
  int base = 2 * g * (g + 1) + (qt - 4 * g) * (g + 1) - 4;
  const u16* bp = part + ((size_t)(h * 140 + base)) * 1280 + tq * 20;
  float L = 0.0f;
  float o[16];
#pragma unroll
  for (int d = 0; d < 16; ++d) o[d] = 0.0f;
  for (int c = 0; c < nc; ++c) {
    const u16* pr = bp + (size_t)c * 1280;
    L += *(const float*)pr;
#pragma unroll
    for (int k = 0; k < 4; ++k) {
      us4 ov = *(const us4*)(pr + 2 + 4 * k);
#pragma unroll
      for (int j = 0; j < 4; ++j) o[4 * k + j] += bf2f(ov[j]);
    }
  }
  float inv = 1.0f / L;
  int q = qt * 64 + tq;
  u16* op = ctx + (size_t)q * D + h * DHD;
#pragma unroll
  for (int k = 0; k < 4; ++k) {
    us4 pk;
#pragma unroll
    for (int j = 0; j < 4; ++j) pk[j] = f2bf(o[4 * k + j] * inv);
    *(us4*)(op + 4 * k) = pk;
  }
}

// ---------------- launcher ----------------
extern "C" void kernel_launch(void* const* d_in, const int* in_sizes, int n_in,
                              void* d_out, int out_size, void* d_ws, size_t ws_size,
                              hipStream_t stream) {
  const float* x = (const float*)d_in[0];
  const float* ln0_g = (const float*)d_in[1];
  const float* ln0_b = (const float*)d_in[2];
  const float* lnq_g = (const float*)d_in[3];
  const float* lnq_b = (const float*)d_in[4];
  const float* lnk_g = (const float*)d_in[5];
  const float* lnk_b = (const float*)d_in[6];
  const float* lnv_g = (const float*)d_in[7];
  const float* lnv_b = (const float*)d_in[8];
  const float* Wq = (const float*)d_in[9];
  const float* bq = (const float*)d_in[10];
  const float* Wk = (const float*)d_in[11];
  const float* bk = (const float*)d_in[12];
  const float* Wv = (const float*)d_in[13];
  const float* bv = (const float*)d_in[14];
  const float* Wo = (const float*)d_in[15];
  const float* bo = (const float*)d_in[16];
  const float* lnf_g = (const float*)d_in[17];
  const float* lnf_b = (const float*)d_in[18];
  const float* W1 = (const float*)d_in[19];
  const float* b1 = (const float*)d_in[20];
  const float* W2 = (const float*)d_in[21];
  const float* b2 = (const float*)d_in[22];

  char* wsp = (char*)d_ws;
  size_t off = 0;
  auto alloc = [&](size_t bytes) -> void* {
    void* p = wsp + off;
    off += (bytes + 255) & ~(size_t)255;
    return p;
  };
  // ---- fixed region (live across attention) ----
  float* xn = (float*)alloc((size_t)S * D * 4);
  u16* Qb = (u16*)alloc((size_t)S * D * 2);
  u16* ctx = (u16*)alloc((size_t)S * D * 2);
  u16* KtG = (u16*)alloc((size_t)S * D * 2);
  u16* VtG = (u16*)alloc((size_t)S * D * 2);
  u16* WfQ = (u16*)alloc((size_t)D * D * 2);
  u16* WfK = (u16*)alloc((size_t)D * D * 2);
  u16* WfV = (u16*)alloc((size_t)D * D * 2);
  u16* WfO = (u16*)alloc((size_t)D * D * 2);
  u16* Wf1 = (u16*)alloc((size_t)D * DFF * 2);
  u16* Wf2 = (u16*)alloc((size_t)DFF * D * 2);
  // ---- multiplexed region B (phases don't overlap in stream order) ----
  char* regB = (char*)alloc((size_t)15 * 1024 * 1024);
  u16* qin = (u16*)regB;                                  // phase 1
  u16* kin = (u16*)(regB + (size_t)S * D * 2);
  u16* vin = (u16*)(regB + (size_t)S * D * 4);
  u16* part = (u16*)regB;                                 // phase 2 (11.47MB)
  float* outb = (float*)regB;                             // phase 3
  u16* hbuf = (u16*)(regB + (size_t)S * D * 6);

  prologue_kernel<<<dim3(2560), 256, 0, stream>>>(
      x, ln0_g, ln0_b, lnq_g, lnq_b, lnk_g, lnk_b, lnv_g, lnv_b, xn, qin, kin, vin,
      Wq, Wk, Wv, Wo, W1, W2, WfQ, WfK, WfV, WfO, Wf1, Wf2);

  gemm_qkv<<<dim3(S / 64, D / 64, 3), 256, 0, stream>>>(
      qin, kin, vin, WfQ, WfK, WfV, bq, bk, bv, Qb, KtG, VtG);

  attn_kernel<<<dim3(144, NH), 128, 0, stream>>>(Qb, KtG, VtG, ctx, part);

  attn_merge<<<dim3(28, NH), 64, 0, stream>>>(part, ctx);

  gemm_kernel<false, true, false><<<dim3(S / 64, D / 64), 256, 0, stream>>>(
      ctx, WfO, bo, xn, outb, nullptr, D, D);

  gemm_ffn1<<<dim3(S / 64, DFF / 64), 256, 0, stream>>>(
      outb, lnf_g, lnf_b, Wf1, b1, hbuf);

  gemm_kernel<true, true, false><<<dim3(S / 64, D / 64), 256, 0, stream>>>(
      hbuf, Wf2, b2, outb, (float*)d_out, nullptr, D, DFF);

  (void)in_sizes; (void)n_in; (void)out_size; (void)ws_size;
}

// Round 11
// 88.200 us; speedup vs baseline: 1.0675x; 1.0675x over previous
//
#include <hip/hip_runtime.h>

#define S 2048
#define D 512
#define NH 32
#define DHD 16
#define DFF 1024
#define EPS 1e-5f
#define C1 0.36067376022224085f  // (1/sqrt(16)) * log2(e), folded into Q

typedef unsigned short u16;
typedef __attribute__((ext_vector_type(8))) short short8;
typedef __attribute__((ext_vector_type(4))) float f32x4;
typedef __attribute__((ext_vector_type(16))) float f32x16;
typedef __attribute__((ext_vector_type(4))) unsigned short us4;

#define GL_LDS(gsrc, ldst)                                                   \
  __builtin_amdgcn_global_load_lds(                                          \
      (const __attribute__((address_space(1))) unsigned int*)(gsrc),         \
      (__attribute__((address_space(3))) unsigned int*)(ldst), 16, 0, 0)

static __device__ __forceinline__ u16 f2bf(float f) {
  union { float f; unsigned int i; } c; c.f = f;
  unsigned int x = c.i;
  return (u16)((x + 0x7fffu + ((x >> 16) & 1u)) >> 16);
}
static __device__ __forceinline__ float bf2f(u16 v) {
  union { unsigned int i; float f; } c; c.i = ((unsigned int)v) << 16;
  return c.f;
}

static __device__ __forceinline__ float tsum16(const float* p) {
  float a0 = p[0] + p[1], a1 = p[2] + p[3], a2 = p[4] + p[5], a3 = p[6] + p[7];
  float a4 = p[8] + p[9], a5 = p[10] + p[11], a6 = p[12] + p[13], a7 = p[14] + p[15];
  float b0 = a0 + a1, b1 = a2 + a3, b2 = a4 + a5, b3 = a6 + a7;
  return (b0 + b1) + (b2 + b3);
}

// ---------------- fused prologue: weight prep + ln0 ----------------
// bz [0,2048): weight fragment prep; [2048,2560): ln0 rows.
__global__ __launch_bounds__(256) void prologue_kernel(
    const float* __restrict__ x,
    const float* __restrict__ g0, const float* __restrict__ b0,
    const float* __restrict__ gq, const float* __restrict__ bq,
    const float* __restrict__ gk, const float* __restrict__ bk,
    const float* __restrict__ gv, const float* __restrict__ bv,
    float* __restrict__ xn, u16* __restrict__ qin, u16* __restrict__ kin,
    u16* __restrict__ vin,
    const float* __restrict__ Wq, const float* __restrict__ Wk,
    const float* __restrict__ Wv, const float* __restrict__ Wo,
    const float* __restrict__ W1, const float* __restrict__ W2,
    u16* __restrict__ Fq, u16* __restrict__ Fk,
    u16* __restrict__ Fv, u16* __restrict__ Fo,
    u16* __restrict__ F1, u16* __restrict__ F2) {
  int bz = blockIdx.x;
  int t = threadIdx.x;
  if (bz < 2048) {
    __shared__ float tile[32][33];
    const float* W;
    u16* F;
    int K, N, n0, k0;
    if (bz < 1024) {
      int wi = bz >> 8, tl = bz & 255;
      W = wi == 0 ? Wq : wi == 1 ? Wk : wi == 2 ? Wv : Wo;
      F = wi == 0 ? Fq : wi == 1 ? Fk : wi == 2 ? Fv : Fo;
      K = 512; N = 512;
      n0 = (tl & 15) * 32; k0 = (tl >> 4) * 32;
    } else if (bz < 1536) {
      int tl = bz - 1024;
      W = W1; F = F1; K = 512; N = 1024;
      n0 = (tl & 31) * 32; k0 = (tl >> 5) * 32;
    } else {
      int tl = bz - 1536;
      W = W2; F = F2; K = 1024; N = 512;
      n0 = (tl & 15) * 32; k0 = (tl >> 4) * 32;
    }
    int tx = t & 31, ty = t >> 5;
#pragma unroll
    for (int i = 0; i < 4; ++i)
      tile[ty + 8 * i][tx] = W[(size_t)(k0 + ty + 8 * i) * N + n0 + tx];
    __syncthreads();
    int k = k0 + tx;
    int kpart = ((k >> 3) & 1) * 32;
    int kj = k & 7;
#pragma unroll
    for (int i = 0; i < 4; ++i) {
      int n = n0 + ty + 8 * i;
      size_t I = (size_t)((n >> 5) * (K >> 4) + (k >> 4)) * 512 + ((n & 31) + kpart) * 8 + kj;
      F[I] = f2bf(tile[tx][ty + 8 * i]);
    }
    return;
  }
  // ---- ln0 ----
  int w = t >> 6, lane = t & 63;
  int row = (bz - 2048) * 4 + w;
  int c = lane * 8;
  const float* xr = x + (size_t)row * D + c;
  float4 xa = *(const float4*)xr;
  float4 xb = *(const float4*)(xr + 4);
  float a[8] = {xa.x, xa.y, xa.z, xa.w, xb.x, xb.y, xb.z, xb.w};
  float s = 0.0f, ss = 0.0f;
#pragma unroll
  for (int i = 0; i < 8; ++i) { s += a[i]; ss += a[i] * a[i]; }
#pragma unroll
  for (int m = 1; m <= 32; m <<= 1) { s += __shfl_xor(s, m); ss += __shfl_xor(ss, m); }
  float mean = s * (1.0f / D);
  float rs = rsqrtf(ss * (1.0f / D) - mean * mean + EPS);
  float4 ga = *(const float4*)(g0 + c), gb = *(const float4*)(g0 + c + 4);
  float4 ba = *(const float4*)(b0 + c), bb = *(const float4*)(b0 + c + 4);
  float gg[8] = {ga.x, ga.y, ga.z, ga.w, gb.x, gb.y, gb.z, gb.w};
  float bbv[8] = {ba.x, ba.y, ba.z, ba.w, bb.x, bb.y, bb.z, bb.w};
  float y[8];
  float s2 = 0.0f, ss2 = 0.0f;
#pragma unroll
  for (int i = 0; i < 8; ++i) {
    y[i] = (a[i] - mean) * rs * gg[i] + bbv[i];
    s2 += y[i]; ss2 += y[i] * y[i];
  }
  float* xo = xn + (size_t)row * D + c;
  *(float4*)xo = {y[0], y[1], y[2], y[3]};
  *(float4*)(xo + 4) = {y[4], y[5], y[6], y[7]};
#pragma unroll
  for (int m = 1; m <= 32; m <<= 1) { s2 += __shfl_xor(s2, m); ss2 += __shfl_xor(ss2, m); }
  float m2 = s2 * (1.0f / D);
  float rs2 = rsqrtf(ss2 * (1.0f / D) - m2 * m2 + EPS);
  float cn[8];
#pragma unroll
  for (int i = 0; i < 8; ++i) cn[i] = (y[i] - m2) * rs2;
  size_t o = (size_t)row * D + c;
#pragma unroll
  for (int br = 0; br < 3; ++br) {
    const float* gp = br == 0 ? gq : br == 1 ? gk : gv;
    const float* bp = br == 0 ? bq : br == 1 ? bk : bv;
    u16* op = br == 0 ? qin : br == 1 ? kin : vin;
    float4 g1 = *(const float4*)(gp + c), g2 = *(const float4*)(gp + c + 4);
    float4 b1 = *(const float4*)(bp + c), b2 = *(const float4*)(bp + c + 4);
    float gv2[8] = {g1.x, g1.y, g1.z, g1.w, g2.x, g2.y, g2.z, g2.w};
    float bv2[8] = {b1.x, b1.y, b1.z, b1.w, b2.x, b2.y, b2.z, b2.w};
    us4 o1, o2;
#pragma unroll
    for (int i = 0; i < 4; ++i) o1[i] = f2bf(cn[i] * gv2[i] + bv2[i]);
#pragma unroll
    for (int i = 0; i < 4; ++i) o2[i] = f2bf(cn[4 + i] * gv2[4 + i] + bv2[4 + i]);
    *(us4*)(op + o) = o1;
    *(us4*)(op + o + 4) = o2;
  }
}

__global__ __launch_bounds__(256) void ln2_kernel(
    const float* __restrict__ in, const float* __restrict__ g,
    const float* __restrict__ b, u16* __restrict__ out) {
  int w = threadIdx.x >> 6, lane = threadIdx.x & 63;
  int row = blockIdx.x * 4 + w;
  int c = lane * 8;
  const float* xr = in + (size_t)row * D + c;
  float4 xa = *(const float4*)xr;
  float4 xb = *(const float4*)(xr + 4);
  float a[8] = {xa.x, xa.y, xa.z, xa.w, xb.x, xb.y, xb.z, xb.w};
  float s = 0.0f, ss = 0.0f;
#pragma unroll
  for (int i = 0; i < 8; ++i) { s += a[i]; ss += a[i] * a[i]; }
#pragma unroll
  for (int m = 1; m <= 32; m <<= 1) { s += __shfl_xor(s, m); ss += __shfl_xor(ss, m); }
  float mean = s * (1.0f / D);
  float rs = rsqrtf(ss * (1.0f / D) - mean * mean + EPS);
  float4 ga = *(const float4*)(g + c), gb = *(const float4*)(g + c + 4);
  float4 ba = *(const float4*)(b + c), bb = *(const float4*)(b + c + 4);
  float gg[8] = {ga.x, ga.y, ga.z, ga.w, gb.x, gb.y, gb.z, gb.w};
  float bbv[8] = {ba.x, ba.y, ba.z, ba.w, bb.x, bb.y, bb.z, bb.w};
  us4 o1, o2;
#pragma unroll
  for (int i = 0; i < 4; ++i) o1[i] = f2bf((a[i] - mean) * rs * gg[i] + bbv[i]);
#pragma unroll
  for (int i = 0; i < 4; ++i) o2[i] = f2bf((a[4 + i] - mean) * rs * gg[4 + i] + bbv[4 + i]);
  *(us4*)(out + (size_t)row * D + c) = o1;
  *(us4*)(out + (size_t)row * D + c + 4) = o2;
}

// ---------------- GEMM: 64x64 block, BK=64, A via global_load_lds, B in regs ----------------
static __device__ __forceinline__ void stageA(const u16* __restrict__ A, int K,
                                              int m0, int kk, u16* As, int t) {
  int r = t >> 3, sl = t & 7;
  GL_LDS(A + (size_t)(m0 + r) * K + kk + ((sl ^ (r & 7)) * 8), As + t * 8);
  int r2 = r + 32;
  GL_LDS(A + (size_t)(m0 + r2) * K + kk + ((sl ^ (r2 & 7)) * 8), As + (t + 256) * 8);
}

static __device__ __forceinline__ void gemm64_acc(
    const u16* __restrict__ A, const u16* __restrict__ Wf, int K, int m0,
    int n32base, u16 (*As)[4096], f32x16& acc) {
  int t = threadIdx.x, w = t >> 6, lane = t & 63;
  int wm = w >> 1, wn = w & 1;
  int l31 = lane & 31, hi5 = lane >> 5;
  const u16* bp = Wf + (size_t)(n32base + wn) * (K >> 4) * 512 + lane * 8;
  stageA(A, K, m0, 0, As[0], t);
  short8 bcur[4], bnxt[4];
#pragma unroll
  for (int ks = 0; ks < 4; ++ks) bcur[ks] = *(const short8*)(bp + ks * 512);
  __syncthreads();
  int pb = 0;
  int arow = wm * 32 + l31;
  int abase = arow * 64;
  for (int kk = 0; kk < K; kk += 64) {
    if (kk + 64 < K) {
      stageA(A, K, m0, kk + 64, As[pb ^ 1], t);
      const u16* bp2 = bp + (size_t)(kk + 64) * 32;
#pragma unroll
      for (int ks = 0; ks < 4; ++ks) bnxt[ks] = *(const short8*)(bp2 + ks * 512);
    }
#pragma unroll
    for (int ks = 0; ks < 4; ++ks) {
      int slot = (ks * 2 + hi5) ^ (arow & 7);
      short8 af = *(const short8*)&As[pb][abase + slot * 8];
      acc = __builtin_amdgcn_mfma_f32_32x32x16_bf16(af, bcur[ks], acc, 0, 0, 0);
    }
    __syncthreads();
    pb ^= 1;
#pragma unroll
    for (int ks = 0; ks < 4; ++ks) bcur[ks] = bnxt[ks];
  }
}

template <bool RELU, bool RESID, bool OUTBF>
__global__ __launch_bounds__(256) void gemm_kernel(
    const u16* __restrict__ A, const u16* __restrict__ Wf,
    const float* __restrict__ bias, const float* __restrict__ resid,
    float* __restrict__ outf, u16* __restrict__ outb, int N, int K) {
  __shared__ u16 As[2][4096];
  int m0 = blockIdx.x * 64, n0 = blockIdx.y * 64;
  f32x16 acc = {};
  gemm64_acc(A, Wf, K, m0, blockIdx.y * 2, As, acc);
  int t = threadIdx.x, w = t >> 6, lane = t & 63;
  int wm = w >> 1, wn = w & 1;
  int l31 = lane & 31, hi5 = lane >> 5;
  int col = n0 + wn * 32 + l31;
  float bv = bias[col];
#pragma unroll
  for (int r = 0; r < 16; ++r) {
    int row = m0 + wm * 32 + (r & 3) + 8 * (r >> 2) + 4 * hi5;
    float v = acc[r] + bv;
    if (RELU) v = fmaxf(v, 0.0f);
    if (RESID) v += resid[(size_t)row * N + col];
    if (OUTBF)
      outb[(size_t)row * N + col] = f2bf(v);
    else
      outf[(size_t)row * N + col] = v;
  }
}

// QKV fused GEMM. z=0: Q row-major (scaled by C1). z=1: K fragment layout.
// z=2: V^T fragment layout (attention reads fragments directly from global).
__global__ __launch_bounds__(256) void gemm_qkv(
    const u16* __restrict__ a0, const u16* __restrict__ a1, const u16* __restrict__ a2,
    const u16* __restrict__ w0, const u16* __restrict__ w1, const u16* __restrict__ w2,
    const float* __restrict__ c0, const float* __restrict__ c1, const float* __restrict__ c2,
    u16* __restrict__ Qb, u16* __restrict__ KtG, u16* __restrict__ VtG) {
  __shared__ u16 As[2][4096];
  int z = blockIdx.z;
  const u16* A = z == 0 ? a0 : z == 1 ? a1 : a2;
  const u16* Wf = z == 0 ? w0 : z == 1 ? w1 : w2;
  const float* bias = z == 0 ? c0 : z == 1 ? c1 : c2;
  int m0 = blockIdx.x * 64, n0 = blockIdx.y * 64;
  f32x16 acc = {};
  gemm64_acc(A, Wf, D, m0, blockIdx.y * 2, As, acc);
  int t = threadIdx.x, w = t >> 6, lane = t & 63;
  int wm = w >> 1, wn = w & 1;
  int l31 = lane & 31, hi5 = lane >> 5;
  int col = n0 + wn * 32 + l31;
  float bv = bias[col];
  int h = col >> 4, d = col & 15;
  if (z == 2) {  // vectorized: 4 consecutive rows are contiguous in V layout
#pragma unroll
    for (int rg = 0; rg < 4; ++rg) {
      int row = m0 + wm * 32 + 8 * rg + 4 * hi5;
      us4 pk;
#pragma unroll
      for (int j = 0; j < 4; ++j) pk[j] = f2bf(acc[rg * 4 + j] + bv);
      int I = (((row >> 5) * 4 + ((row >> 3) & 3)) * 16 + d) * 8 + (row & 7);
      *(us4*)(VtG + (size_t)h * 32768 + I) = pk;
    }
  } else {
#pragma unroll
    for (int r = 0; r < 16; ++r) {
      int row = m0 + wm * 32 + (r & 3) + 8 * (r >> 2) + 4 * hi5;
      float v = acc[r] + bv;
      if (z == 0) {
        Qb[(size_t)row * D + col] = f2bf(v * C1);
      } else {
        int I = (((row >> 5) * 2 + (d >> 3)) * 32 + (row & 31)) * 8 + (d & 7);
        KtG[(size_t)h * 32768 + I] = f2bf(v);
      }
    }
  }
}

// ---------------- causal flash attention, split-KV, no-max softmax ----------------
__global__ __launch_bounds__(128) void attn_kernel(const u16* __restrict__ Qb,
                                                   const u16* __restrict__ KtG,
                                                   const u16* __restrict__ VtG,
                                                   u16* __restrict__ ctx,
                                                   u16* __restrict__ part) {
  __shared__ u16 Pl[2][2048];

  const int t = threadIdx.x, w = t >> 6, lane = t & 63;
  const int h = blockIdx.y;
  const int f = 143 - blockIdx.x;  // longest chunks dispatched first
  int g = (int)((sqrtf((float)(1 + 2 * f)) - 1.0f) * 0.5f);
  while (2 * (g + 1) * (g + 2) <= f) ++g;
  while (2 * g * (g + 1) > f) --g;
  const int fg = f - 2 * g * (g + 1);
  const int qt = 4 * g + fg / (g + 1);
  const int c = fg - (fg / (g + 1)) * (g + 1);
  const int t0 = 4 * c;
  const int t1 = (4 * c + 3 < qt) ? 4 * c + 3 : qt;

  const int q0w = qt * 64 + w * 32;
  const int lq = lane & 31, hi = lane >> 5;
  const int l16 = lane & 15, g4 = lane >> 4;

  short8 qf = *(const short8*)(Qb + (size_t)(q0w + lq) * D + h * DHD + hi * 8);
  const u16* kp = KtG + (size_t)h * 32768 + (size_t)t0 * 1024 + hi * 256 + lq * 8;
  const u16* vp = VtG + (size_t)h * 32768 + (size_t)t0 * 1024 + g4 * 128 + l16 * 8;

  f32x4 acc[2] = {};
  float Lrun = 0.0f;

  short8 kf0 = *(const short8*)kp;
  short8 kf1 = *(const short8*)(kp + 512);
  short8 vf0 = *(const short8*)vp;
  short8 vf1 = *(const short8*)(vp + 512);

  u16* Pw = &Pl[w][0];
  const int pwr = (lq >> 4) * 1024 + (lq & 15) * 8 + 4 * hi;  // P write base
  const int prd = g4 * 128 + l16 * 8;                          // P read base

  for (int tt = t0; tt <= t1; ++tt) {
    const int kv0 = tt * 64;
    const bool v1 = (kv0 + 32) <= (q0w + 31);
    f32x16 z = {};
    f32x16 st0 = __builtin_amdgcn_mfma_f32_32x32x16_bf16(kf0, qf, z, 0, 0, 0);
    f32x16 st1 = z;
    if (v1) st1 = __builtin_amdgcn_mfma_f32_32x32x16_bf16(kf1, qf, z, 0, 0, 0);

    short8 nk0, nk1, nv0, nv1;
    const bool more = (tt < t1);
    if (more) {  // issue next-tile loads early; they hide under softmax
      kp += 1024; vp += 1024;
      nk0 = *(const short8*)kp;
      nk1 = *(const short8*)(kp + 512);
      nv0 = *(const short8*)vp;
      nv1 = *(const short8*)(vp + 512);
    }

    // ---- mask (diag tiles) + exp2, no max subtraction ----
    float p0[16], p1[16];
    const int thr0 = q0w + lq - kv0 - 4 * hi;
    if (kv0 + 31 > q0w) {
#pragma unroll
      for (int r = 0; r < 16; ++r) {
        const int rc = (r & 3) + 8 * (r >> 2);
        p0[r] = (rc > thr0) ? -1e30f : st0[r];
      }
    } else {
#pragma unroll
      for (int r = 0; r < 16; ++r) p0[r] = st0[r];
    }
#pragma unroll
    for (int r = 0; r < 16; ++r) p0[r] = exp2f(p0[r]);
    float sum = tsum16(p0);
    if (v1) {
      const int thr1 = thr0 - 32;
      if (kv0 + 63 > q0w) {
#pragma unroll
        for (int r = 0; r < 16; ++r) {
          const int rc = (r & 3) + 8 * (r >> 2);
          p1[r] = (rc > thr1) ? -1e30f : st1[r];
        }
      } else {
#pragma unroll
        for (int r = 0; r < 16; ++r) p1[r] = st1[r];
      }
#pragma unroll
      for (int r = 0; r < 16; ++r) p1[r] = exp2f(p1[r]);
      sum += tsum16(p1);
    }
    sum += __shfl_xor(sum, 32);
    Lrun += sum;

    // ---- pack P (cvt_pk) into swizzled per-wave LDS ----
#pragma unroll
    for (int k = 0; k < 4; ++k) {
      unsigned int w0, w1;
      asm("v_cvt_pk_bf16_f32 %0, %1, %2" : "=v"(w0) : "v"(p0[4 * k]), "v"(p0[4 * k + 1]));
      asm("v_cvt_pk_bf16_f32 %0, %1, %2" : "=v"(w1) : "v"(p0[4 * k + 2]), "v"(p0[4 * k + 3]));
      uint2 pv; pv.x = w0; pv.y = w1;
      *(uint2*)&Pw[(pwr + k * 128) ^ (k << 4)] = pv;
    }
    if (v1) {
#pragma unroll
      for (int k = 0; k < 4; ++k) {
        unsigned int w0, w1;
        asm("v_cvt_pk_bf16_f32 %0, %1, %2" : "=v"(w0) : "v"(p1[4 * k]), "v"(p1[4 * k + 1]));
        asm("v_cvt_pk_bf16_f32 %0, %1, %2" : "=v"(w1) : "v"(p1[4 * k + 2]), "v"(p1[4 * k + 3]));
        uint2 pv; pv.x = w0; pv.y = w1;
        *(uint2*)&Pw[(pwr + 512 + k * 128) ^ (k << 4)] = pv;
      }
    }

    // ---- PV (V fragments live in registers) ----
#pragma unroll
    for (int sx = 0; sx < 2; ++sx) {
      if (sx == 0 || v1) {
        short8 vf = sx ? vf1 : vf0;
#pragma unroll
        for (int sq = 0; sq < 2; ++sq) {
          short8 pf = *(const short8*)&Pw[(sq * 1024 + sx * 512 + prd) ^ (g4 << 4)];
          acc[sq] = __builtin_amdgcn_mfma_f32_16x16x32_bf16(pf, vf, acc[sq], 0, 0, 0);
        }
      }
    }

    if (more) { kf0 = nk0; kf1 = nk1; vf0 = nv0; vf1 = nv1; }
  }

  if (g == 0) {  // single chunk: direct output
#pragma unroll
    for (int sq = 0; sq < 2; ++sq)
#pragma unroll
      for (int r = 0; r < 4; ++r) {
        int qlr = sq * 16 + g4 * 4 + r;
        float lv = __shfl(Lrun, qlr);
        float inv = __builtin_amdgcn_rcpf(lv);
        ctx[(size_t)(q0w + qlr) * D + h * DHD + l16] = f2bf(acc[sq][r] * inv);
      }
  } else {
    // partial row: 20 u16 = [L f32][16 x bf16 O][pad]
    const int pslot = 2 * g * (g + 1) + (qt - 4 * g) * (g + 1) - 4 + c;
    u16* ps = part + ((size_t)(h * 140 + pslot)) * 1280;
#pragma unroll
    for (int sq = 0; sq < 2; ++sq)
#pragma unroll
      for (int r = 0; r < 4; ++r) {
        int qlocal = w * 32 + sq * 16 + g4 * 4 + r;
        ps[qlocal * 20 + 2 + l16] = f2bf(acc[sq][r]);
      }
    if (hi == 0) {
      *(float*)(ps + (w * 32 + lq) * 20) = Lrun;
    }
  }
}

// ---------------- merge split-KV partials (qt >= 4): pure (O,L) sums ----------------
__global__ __launch_bounds__(64) void attn_merge(const u16* __restrict__ part,
                                                 u16* __restrict__ ctx) {
  int qt = 4 + blockIdx.x, h = blockIdx.y, tq = threadIdx.x;
  int g = qt >> 2, nc = g + 1;
  int base = 2 * g * (g + 1) + (qt - 4 * g) * (g + 1) - 4;
  const u16* bp = part + ((size_t)(h * 140 + base)) * 1280 + tq * 20;
  float L = 0.0f;
  float o[16];
#pragma unroll
  for (int d = 0; d < 16; ++d) o[d] = 0.0f;
  for (int c = 0; c < nc; ++c) {
    const u16* pr = bp + (size_t)c * 1280;
    L += *(const float*)pr;
#pragma unroll
    for (int k = 0; k < 4; ++k) {
      us4 ov = *(const us4*)(pr + 2 + 4 * k);
#pragma unroll
      for (int j = 0; j < 4; ++j) o[4 * k + j] += bf2f(ov[j]);
    }
  }
  float inv = 1.0f / L;
  int q = qt * 64 + tq;
  u16* op = ctx + (size_t)q * D + h * DHD;
#pragma unroll
  for (int k = 0; k < 4; ++k) {
    us4 pk;
#pragma unroll
    for (int j = 0; j < 4; ++j) pk[j] = f2bf(o[4 * k + j] * inv);
    *(us4*)(op + 4 * k) = pk;
  }
}

// ---------------- launcher ----------------
extern "C" void kernel_launch(void* const* d_in, const int* in_sizes, int n_in,
                              void* d_out, int out_size, void* d_ws, size_t ws_size,
                              hipStream_t stream) {
  const float* x = (const float*)d_in[0];
  const float* ln0_g = (const float*)d_in[1];
  const float* ln0_b = (const float*)d_in[2];
  const float* lnq_g = (const float*)d_in[3];
  const float* lnq_b = (const float*)d_in[4];
  const float* lnk_g = (const float*)d_in[5];
  const float* lnk_b = (const float*)d_in[6];
  const float* lnv_g = (const float*)d_in[7];
  const float* lnv_b = (const float*)d_in[8];
  const float* Wq = (const float*)d_in[9];
  const float* bq = (const float*)d_in[10];
  const float* Wk = (const float*)d_in[11];
  const float* bk = (const float*)d_in[12];
  const float* Wv = (const float*)d_in[13];
  const float* bv = (const float*)d_in[14];
  const float* Wo = (const float*)d_in[15];
  const float* bo = (const float*)d_in[16];
  const float* lnf_g = (const float*)d_in[17];
  const float* lnf_b = (const float*)d_in[18];
  const float* W1 = (const float*)d_in[19];
  const float* b1 = (const float*)d_in[20];
  const float* W2 = (const float*)d_in[21];
  const float* b2 = (const float*)d_in[22];

  char* wsp = (char*)d_ws;
  size_t off = 0;
  auto alloc = [&](size_t bytes) -> void* {
    void* p = wsp + off;
    off += (bytes + 255) & ~(size_t)255;
    return p;
  };
  // ---- fixed region (live across attention) ----
  float* xn = (float*)alloc((size_t)S * D * 4);
  u16* Qb = (u16*)alloc((size_t)S * D * 2);
  u16* ctx = (u16*)alloc((size_t)S * D * 2);
  u16* KtG = (u16*)alloc((size_t)S * D * 2);
  u16* VtG = (u16*)alloc((size_t)S * D * 2);
  u16* WfQ = (u16*)alloc((size_t)D * D * 2);
  u16* WfK = (u16*)alloc((size_t)D * D * 2);
  u16* WfV = (u16*)alloc((size_t)D * D * 2);
  u16* WfO = (u16*)alloc((size_t)D * D * 2);
  u16* Wf1 = (u16*)alloc((size_t)D * DFF * 2);
  u16* Wf2 = (u16*)alloc((size_t)DFF * D * 2);
  // ---- multiplexed region B (phases don't overlap in stream order) ----
  char* regB = (char*)alloc((size_t)15 * 1024 * 1024);
  u16* qin = (u16*)regB;                                  // phase 1
  u16* kin = (u16*)(regB + (size_t)S * D * 2);
  u16* vin = (u16*)(regB + (size_t)S * D * 4);
  u16* part = (u16*)regB;                                 // phase 2 (11.47MB)
  float* outb = (float*)regB;                             // phase 3
  u16* lnf = (u16*)(regB + (size_t)S * D * 4);
  u16* hbuf = (u16*)(regB + (size_t)S * D * 6);

  prologue_kernel<<<dim3(2560), 256, 0, stream>>>(
      x, ln0_g, ln0_b, lnq_g, lnq_b, lnk_g, lnk_b, lnv_g, lnv_b, xn, qin, kin, vin,
      Wq, Wk, Wv, Wo, W1, W2, WfQ, WfK, WfV, WfO, Wf1, Wf2);

  gemm_qkv<<<dim3(S / 64, D / 64, 3), 256, 0, stream>>>(
      qin, kin, vin, WfQ, WfK, WfV, bq, bk, bv, Qb, KtG, VtG);

  attn_kernel<<<dim3(144, NH), 128, 0, stream>>>(Qb, KtG, VtG, ctx, part);

  attn_merge<<<dim3(28, NH), 64, 0, stream>>>(part, ctx);

  gemm_kernel<false, true, false><<<dim3(S / 64, D / 64), 256, 0, stream>>>(
      ctx, WfO, bo, xn, outb, nullptr, D, D);

  ln2_kernel<<<S / 4, 256, 0, stream>>>(outb, lnf_g, lnf_b, lnf);

  gemm_kernel<true, false, true><<<dim3(S / 64, DFF / 64), 256, 0, stream>>>(
      lnf, Wf1, b1, nullptr, nullptr, hbuf, DFF, D);

  gemm_kernel<true, true, false><<<dim3(S / 64, D / 64), 256, 0, stream>>>(
      hbuf, Wf2, b2, outb, (float*)d_out, nullptr, D, DFF);

  (void)in_sizes; (void)n_in; (void)out_size; (void)ws_size;
}